// Round 16
// baseline (6911.855 us; speedup 1.0000x reference)
//
#include <hip/hip_runtime.h>

typedef unsigned int u32;
typedef unsigned short u16;
typedef __attribute__((ext_vector_type(4))) u32 u32x4;
typedef __attribute__((ext_vector_type(4))) u16 u16x4;
typedef __attribute__((ext_vector_type(8))) short bf16x8;
typedef __attribute__((ext_vector_type(4))) float f32x4;
typedef __attribute__((ext_vector_type(2))) _Float16 h2f;

#define NSC 8          // scan blocks
#define SLICE 32       // e per scan block
#define ROWS 128       // 4 gates * SLICE preact rows per block

__device__ __forceinline__ u16 f2bf(float x){
  u32 u = __builtin_bit_cast(u32, x);
  u = (u + 0x7fffu + ((u >> 16) & 1u)) >> 16;
  return (u16)u;
}
__device__ __forceinline__ u16 f2h(float x){
  _Float16 h = (_Float16)x;
  return __builtin_bit_cast(u16, h);
}
__device__ __forceinline__ float h2fl(u16 v){ return (float)__builtin_bit_cast(_Float16, v); }
__device__ __forceinline__ h2f as_h2(u32 v){ return __builtin_bit_cast(h2f, v); }
__device__ __forceinline__ float sigf(float x){ return 1.0f/(1.0f + __expf(-x)); }
__device__ __forceinline__ float tanh_f(float x){ float e = __expf(2.0f*x); return 1.0f - 2.0f/(e + 1.0f); }

__device__ __forceinline__ float dot2acc(u32 a, u32 b, float acc){
#if __has_builtin(__builtin_amdgcn_fdot2)
  return __builtin_amdgcn_fdot2(as_h2(a), as_h2(b), acc, false);
#else
  h2f ha = as_h2(a), hb = as_h2(b);
  return acc + (float)ha[0]*(float)hb[0] + (float)ha[1]*(float)hb[1];
#endif
}
__device__ __forceinline__ float dot4(u32x4 u, u32x4 h, float acc){
  acc = dot2acc(u[0], h[0], acc); acc = dot2acc(u[1], h[1], acc);
  acc = dot2acc(u[2], h[2], acc); acc = dot2acc(u[3], h[3], acc);
  return acc;
}

// ---------------- conversion kernels ----------------

// x (1024 x 50001) f32 -> xb (1024 x 50176) bf16, zero-pad cols [50000,50176)
__global__ void conv_x(const float* __restrict__ x, u16* __restrict__ xb){
  int col4 = (blockIdx.x*256 + threadIdx.x)*4;   // grid (49, 1024)
  int row  = blockIdx.y;
  const float* src = x + (long)row*50001 + col4;
  u16x4 v;
  if (col4 < 50000) { v[0]=f2bf(src[0]); v[1]=f2bf(src[1]); v[2]=f2bf(src[2]); v[3]=f2bf(src[3]); }
  else { v[0]=0; v[1]=0; v[2]=0; v[3]=0; }
  *(u16x4*)(xb + (long)row*50176 + col4) = v;
}

// enc_w1 (512 x 50000) f32 -> w1b (512 x 50176) bf16 padded
__global__ void conv_w1(const float* __restrict__ w, u16* __restrict__ wb){
  int col4 = (blockIdx.x*256 + threadIdx.x)*4;   // grid (49, 512)
  int row  = blockIdx.y;
  const float* src = w + (long)row*50000 + col4;
  u16x4 v;
  if (col4 < 50000) { v[0]=f2bf(src[0]); v[1]=f2bf(src[1]); v[2]=f2bf(src[2]); v[3]=f2bf(src[3]); }
  else { v[0]=0; v[1]=0; v[2]=0; v[3]=0; }
  *(u16x4*)(wb + (long)row*50176 + col4) = v;
}

// enc_w2 (256x512), dec_w1 (512x256), gate W_w stacked -> bf16
__global__ void conv_misc(const float* __restrict__ enc_w2, const float* __restrict__ dec_w1,
                          const float* __restrict__ dw, const float* __restrict__ iw,
                          const float* __restrict__ ow, const float* __restrict__ cw,
                          u16* __restrict__ w2eb, u16* __restrict__ wd1b, u16* __restrict__ wgb){
  int idx = blockIdx.x*256 + threadIdx.x;        // grid 2048
  if (idx < 131072) {
    w2eb[idx] = f2bf(enc_w2[idx]);
  } else if (idx < 262144) {
    int i = idx - 131072;
    wd1b[i] = f2bf(dec_w1[i]);
  } else {
    int i = idx - 262144;                        // 262144 elems: wgb[o][k], o = g*256+e
    int o = i >> 8, k = i & 255;
    int g = o >> 8, e = o & 255;
    const float* W = (g==0) ? dw : (g==1) ? iw : (g==2) ? ow : cw;
    wgb[i] = f2bf(W[e*256 + k]);
  }
}

// combined gate biases: bws[o] = u_b[e] + w_b[e]
__global__ void pack_bias(const float* dub, const float* dwb, const float* iub, const float* iwb,
                          const float* oub, const float* owb, const float* cub, const float* cwb,
                          float* __restrict__ bws){
  int o = blockIdx.x*256 + threadIdx.x;          // grid 4
  int g = o >> 8, e = o & 255;
  float v;
  if      (g==0) v = dub[e] + dwb[e];
  else if (g==1) v = iub[e] + iwb[e];
  else if (g==2) v = oub[e] + owb[e];
  else           v = cub[e] + cwb[e];
  bws[o] = v;
}

// Pack U for register residency in the scan (r13 layout, proven VGPR-safe).
// Block b, thread t: rq=t>>3 -> rows lr0=2rq, lr1=2rq+1 (lr in [0,128): gate
// g=lr>>5, e=b*32+(lr&31)); kc=t&7 -> k in [kc*32,(kc+1)*32).
// Quad q: row lr0 (q<4) / lr1 (q>=4), k-sub (q&3)*8 + [0,8) as 4 f16x2 words.
__global__ void pack_u(const float* du, const float* iu, const float* ou, const float* cu,
                       u32* __restrict__ upak){
  int b = blockIdx.x;                            // grid NSC x 512
  int t = threadIdx.x;
  int rq = t >> 3, kc = t & 7;
  for (int q = 0; q < 8; ++q) {
    int lr = 2*rq + (q >> 2);
    int g = lr >> 5, e = b*SLICE + (lr & 31);
    const float* U = (g==0) ? du : (g==1) ? iu : (g==2) ? ou : cu;
    const float* row = U + e*256 + kc*32 + (q & 3)*8;
    for (int p = 0; p < 4; ++p) {
      u32 lo = f2h(row[p*2]);
      u32 hi = f2h(row[p*2+1]);
      upak[((long)(b*512 + t)*8 + q)*4 + p] = lo | (hi << 16);
    }
  }
}

// ---------------- MFMA GEMM: C = A @ B^T, A[M][K] bf16, B[N][K] bf16 ----------------
// EPI: 0 = store f32 partial at Cf + z*1024*ldc (split-K)
//      1 = bias + relu -> bf16 Cb
//      2 = bias -> f32 Cf
//      3 = bias + sigmoid -> f32 Cf with col < nGuard
template<int EPI>
__global__ __launch_bounds__(256)
void gemm_bt(const u16* __restrict__ A, const u16* __restrict__ B,
             const float* __restrict__ bias, float* __restrict__ Cf, u16* __restrict__ Cb,
             int lda, int ldb, int ldc, int kiters, int nGuard){
  __shared__ u16 As[128*32];
  __shared__ u16 Bs[128*32];
  const int tid = threadIdx.x;
  const int l = tid & 63;
  const int w = tid >> 6;
  const int wr = w >> 1, wc = w & 1;             // 2x2 wave grid, 64x64 per wave
  const long kchunk = (long)blockIdx.z * kiters * 32;
  const u16* Ab = A + (long)blockIdx.x*128*lda + kchunk;
  const u16* Bb = B + (long)blockIdx.y*128*ldb + kchunk;
  f32x4 acc[4][4];
#pragma unroll
  for (int m=0;m<4;m++)
#pragma unroll
    for (int n=0;n<4;n++) acc[m][n] = (f32x4){0.f,0.f,0.f,0.f};

  const int lr = l & 15, lk = l >> 4;
  for (int it = 0; it < kiters; ++it) {
    {
      int s = tid;
      int row = s >> 2, kg = s & 3;
      u32x4 va = *(const u32x4*)(Ab + (long)row*lda + (long)it*32 + kg*8);
      u32x4 vb = *(const u32x4*)(Bb + (long)row*ldb + (long)it*32 + kg*8);
      int sw = ((kg + row) & 3) * 8;
      *(u32x4*)&As[row*32 + sw] = va;
      *(u32x4*)&Bs[row*32 + sw] = vb;
      s = tid + 256;
      row = s >> 2; kg = s & 3;
      va = *(const u32x4*)(Ab + (long)row*lda + (long)it*32 + kg*8);
      vb = *(const u32x4*)(Bb + (long)row*ldb + (long)it*32 + kg*8);
      sw = ((kg + row) & 3) * 8;
      *(u32x4*)&As[row*32 + sw] = va;
      *(u32x4*)&Bs[row*32 + sw] = vb;
    }
    __syncthreads();
    bf16x8 af[4], bfr[4];
#pragma unroll
    for (int m=0;m<4;m++) {
      int row = wr*64 + m*16 + lr;
      af[m] = *(const bf16x8*)&As[row*32 + (((lk + row)&3)*8)];
    }
#pragma unroll
    for (int n=0;n<4;n++) {
      int row = wc*64 + n*16 + lr;
      bfr[n] = *(const bf16x8*)&Bs[row*32 + (((lk + row)&3)*8)];
    }
#pragma unroll
    for (int m=0;m<4;m++)
#pragma unroll
      for (int n=0;n<4;n++)
        acc[m][n] = __builtin_amdgcn_mfma_f32_16x16x32_bf16(af[m], bfr[n], acc[m][n], 0, 0, 0);
    __syncthreads();
  }
#pragma unroll
  for (int m=0;m<4;m++) {
#pragma unroll
    for (int n=0;n<4;n++) {
#pragma unroll
      for (int v=0;v<4;v++) {
        int r  = wr*64 + m*16 + lk*4 + v;
        int cn = wc*64 + n*16 + lr;
        long gr = (long)blockIdx.x*128 + r;
        long gc = (long)blockIdx.y*128 + cn;
        float val = acc[m][n][v];
        if (EPI == 0) {
          Cf[((long)blockIdx.z*1024 + gr)*ldc + gc] = val;
        } else if (EPI == 1) {
          float y = val + bias[gc];
          y = y > 0.f ? y : 0.f;
          Cb[gr*ldc + gc] = f2bf(y);
        } else if (EPI == 2) {
          Cf[gr*ldc + gc] = val + bias[gc];
        } else if (EPI == 3) {
          if (gc < nGuard) Cf[gr*ldc + gc] = sigf(val + bias[gc]);
        }
      }
    }
  }
}

// sum split-K partials + bias + relu -> bf16 h1b
__global__ void reduce1(const float* __restrict__ P, const float* __restrict__ b1,
                        u16* __restrict__ h1b){
  int idx = blockIdx.x*256 + threadIdx.x;        // grid 2048 -> 524288 = 1024*512
  float s = b1[idx & 511];
#pragma unroll
  for (int kc = 0; kc < 32; ++kc) s += P[(long)kc*524288 + idx];
  h1b[idx] = f2bf(s > 0.f ? s : 0.f);
}

// ---------------- 8-block cooperative scan: direct per-thread mailbox fetch ----------------
// r15 HUNG: hand-rolled `global_load ... sc0` polls read the reader's LOCAL
// XCD L2, which is never updated by a remote writer (per-XCD L2s are not
// coherent, G16) -> infinite spin. The fix is the transport r11/r13 proved:
// __hip_atomic_load(RELAXED, AGENT) -- the compiler emits the correct
// coherent-load cache bits. The r15 structure is kept:
//  * Each thread fetches ITS 32 h-words (one block's slice) directly from the
//    self-validating mailbox (32 independent pipelined atomic loads, one
//    drain), tag-checks all 32, retries the batch. The poll IS the data load;
//    no LDS staging, no poll barrier -- fetch overlaps straggler skew.
//  * 90 KB LDS pad forces 1 block/CU (no converter co-residency jitter).
//  * U in 8 named register quads (r13-proven), phase B segmented (r13).
// Race-freedom (r11 argument): block X overwrites parity p=st&1 only in its
// step-(st+1) phase B, gated (pre-phase-B barrier + all-tags-(st+1) fetch) on
// every block having completed its step-st fetch of parity p. Mailbox zeroed
// per launch -> tag 0 never matches st>=1; 0xAA poison tag 0xAAAA never
// matches st<=1024 either.
__global__ __launch_bounds__(512) __attribute__((amdgpu_waves_per_eu(2,2)))
void scan_kernel(const u32* __restrict__ upak, const float* __restrict__ xw,
                 u16* __restrict__ hsb, const float* __restrict__ dec_w2,
                 u16* __restrict__ w2db, u32* __restrict__ hmail){
  __shared__ float preact[ROWS];                 // 512 B
  __shared__ u16   hist[50*34];                  // 3400 B, stride 34, cols [0,32) used
  __shared__ float inv_lds[50];                  // 1/k table
  __shared__ char  cu_pad[92160];                // occupancy limiter: 1 block/CU
  const int b = blockIdx.x;
  const int t = threadIdx.x;
  ((volatile char*)cu_pad)[t & 1023] = 1;        // keep pad allocated (volatile)

  if (b >= NSC) {
    // dec_w2 (50000x512) f32 -> w2db (50048x512) bf16, rows >= 50000 zeroed.
    const long total = (50048L*512)/4;           // u16x4 groups
    const long stride = (long)(gridDim.x - NSC)*512;
    for (long g2 = (long)(b-NSC)*512 + t; g2 < total; g2 += stride) {
      long base = g2*4;
      long row = base >> 9;
      u16x4 v;
      if (row < 50000) {
        const float* s = dec_w2 + base;
        v[0]=f2bf(s[0]); v[1]=f2bf(s[1]); v[2]=f2bf(s[2]); v[3]=f2bf(s[3]);
      } else { v[0]=0; v[1]=0; v[2]=0; v[3]=0; }
      *(u16x4*)(w2db + base) = v;
    }
    return;
  }

  const int kc = t & 7;                          // phase A: k-chunk of 32 (= slice kc)
  const int rq = t >> 3;                         // phase A: rows 2rq, 2rq+1
  const int e_loc = t >> 3;                      // phase B (t<256): element (<32)
  const int tau = t & 7;                         // phase B lane-in-group
  const int e_glob = b*SLICE + (e_loc & (SLICE-1));

  // ---- U into registers: 8 named quads (32 VGPRs), loaded once (r13-proven) ----
  const long ubase = (long)(b*512 + t)*32;
  u32x4 Uq0 = *(const u32x4*)(upak + ubase + 0);
  u32x4 Uq1 = *(const u32x4*)(upak + ubase + 4);
  u32x4 Uq2 = *(const u32x4*)(upak + ubase + 8);
  u32x4 Uq3 = *(const u32x4*)(upak + ubase + 12);
  u32x4 Uq4 = *(const u32x4*)(upak + ubase + 16);
  u32x4 Uq5 = *(const u32x4*)(upak + ubase + 20);
  u32x4 Uq6 = *(const u32x4*)(upak + ubase + 24);
  u32x4 Uq7 = *(const u32x4*)(upak + ubase + 28);

  for (int i = t; i < 50*34; i += 512) hist[i] = 0;
  if (t < 50) inv_lds[t] = (t == 0) ? 1.0f : (1.0f/(float)t);
  __syncthreads();

  // xw for st=0 preloaded; in-loop prefetch st+1 (consumed next iteration)
  float xg0=0.f, xg1=0.f, xg2=0.f, xg3=0.f;
  if (t < 256) {
    xg0 = xw[e_glob]; xg1 = xw[256 + e_glob]; xg2 = xw[512 + e_glob]; xg3 = xw[768 + e_glob];
  }

  for (int st = 0; st < 1024; ++st) {
    // prefetch xw(st+1): issued first so its HBM latency hides under the fetch
    float xn0=0.f, xn1=0.f, xn2=0.f, xn3=0.f;
    if (st < 1023 && t < 256) {
      const float* xp = xw + (st+1)*1024;
      xn0 = xp[e_glob]; xn1 = xp[256 + e_glob]; xn2 = xp[512 + e_glob]; xn3 = xp[768 + e_glob];
    }
    // ---- fetch h(st): 32 pipelined agent-coherent loads of this thread's k-chunk ----
    u32x4 h0, h1, h2, h3;                        // packed f16x2 for fdot2
    if (st == 0) {
      h0 = h1 = h2 = h3 = (u32x4){0,0,0,0};
    } else {
      const u32* fb = hmail + ((st&1)<<8) + (kc<<5);
      const u32 e16 = ((u32)st) << 16;
      u32 W[32];
      for (;;) {
#pragma unroll
        for (int i = 0; i < 32; ++i)
          W[i] = __hip_atomic_load(fb + i, __ATOMIC_RELAXED, __HIP_MEMORY_SCOPE_AGENT);
        u32 bad = 0;
#pragma unroll
        for (int i = 0; i < 32; ++i) bad |= W[i] ^ e16;
        if (!(bad & 0xFFFF0000u)) break;
      }
      h0 = (u32x4){ (W[ 1]<<16)|(W[ 0]&0xFFFFu), (W[ 3]<<16)|(W[ 2]&0xFFFFu),
                    (W[ 5]<<16)|(W[ 4]&0xFFFFu), (W[ 7]<<16)|(W[ 6]&0xFFFFu) };
      h1 = (u32x4){ (W[ 9]<<16)|(W[ 8]&0xFFFFu), (W[11]<<16)|(W[10]&0xFFFFu),
                    (W[13]<<16)|(W[12]&0xFFFFu), (W[15]<<16)|(W[14]&0xFFFFu) };
      h2 = (u32x4){ (W[17]<<16)|(W[16]&0xFFFFu), (W[19]<<16)|(W[18]&0xFFFFu),
                    (W[21]<<16)|(W[20]&0xFFFFu), (W[23]<<16)|(W[22]&0xFFFFu) };
      h3 = (u32x4){ (W[25]<<16)|(W[24]&0xFFFFu), (W[27]<<16)|(W[26]&0xFFFFu),
                    (W[29]<<16)|(W[28]&0xFFFFu), (W[31]<<16)|(W[30]&0xFFFFu) };
    }
    __syncthreads();                             // prev phase B done -> preact writable

    // ---- phase A: preact[lr] = sum_k U[lr][k] * h[k] (register U, register h) ----
    {
      float a0 = 0.f, a1 = 0.f;
      a0 = dot4(Uq0, h0, a0); a0 = dot4(Uq1, h1, a0);
      a0 = dot4(Uq2, h2, a0); a0 = dot4(Uq3, h3, a0);
      a1 = dot4(Uq4, h0, a1); a1 = dot4(Uq5, h1, a1);
      a1 = dot4(Uq6, h2, a1); a1 = dot4(Uq7, h3, a1);
      a0 += __shfl_xor(a0,1); a0 += __shfl_xor(a0,2); a0 += __shfl_xor(a0,4);
      a1 += __shfl_xor(a1,1); a1 += __shfl_xor(a1,2); a1 += __shfl_xor(a1,4);
      if (kc == 0) { preact[2*rq] = a0; preact[2*rq+1] = a1; }
    }
    __syncthreads();

    // ---- phase B (t<256): 8 lanes per element ----
    if (t < 256) {
      float pd = preact[0*SLICE + e_loc] + xg0;
      float pi = preact[1*SLICE + e_loc] + xg1;
      float po = preact[2*SLICE + e_loc] + xg2;
      float pc = preact[3*SLICE + e_loc] + xg3;
      float d  = 0.5f * sigf(pd);
      float gi = sigf(pi);
      float go = sigf(po);
      float ct = tanh_f(pc);
      float cur = gi * ct;
      // w_k = prod_{j<k} (d+j)/(j+1)  (== exp(gammaln(d+k)-gammaln(d)-gammaln(k+1)))
      // segmented product-scan: lane tau covers k in [7tau+1, 7tau+7]; tau=7 idle.
      float c = 1.f;
      if (tau < 7) {
#pragma unroll
        for (int m = 0; m < 7; ++m) {
          int j = 7*tau + m;                     // j <= 48
          c *= (d + (float)j) * inv_lds[j+1];
        }
      }
      float v = c;
      float s1 = __shfl_up(v,1,8); if (tau >= 1) v *= s1;
      float s2 = __shfl_up(v,2,8); if (tau >= 2) v *= s2;
      float s4 = __shfl_up(v,4,8); if (tau >= 4) v *= s4;
      float S = __shfl_up(v,1,8); if (tau == 0) S = 1.f;   // S = w_{7tau}
      int base = st % 50;
      float r = S, memp = 0.f;
      if (tau < 7) {
#pragma unroll
        for (int m = 0; m < 7; ++m) {
          int k = 7*tau + 1 + m;                 // 1..49
          r *= (d + (float)(k-1)) * inv_lds[k];  // r = w_k
          int sl = base - k; if (sl < 0) sl += 50;
          memp += r * h2fl(hist[sl*34 + e_loc]);
        }
      }
      memp += __shfl_xor(memp,1,8); memp += __shfl_xor(memp,2,8); memp += __shfl_xor(memp,4,8);
      float mem = memp + cur;                    // + k=0 term (w_0 = 1)
      float hnew = go * tanh_f(mem);
      if (tau == 0) {
        // publish FIRST (critical path), then local/bookkeeping stores
        __hip_atomic_store(hmail + ((((st+1)&1))<<8) + e_glob,
                           (((u32)(st+1)) << 16) | (u32)f2h(hnew),
                           __ATOMIC_RELAXED, __HIP_MEMORY_SCOPE_AGENT);
        hist[base*34 + e_loc] = f2h(cur);
        hsb[st*256 + e_glob] = f2bf(hnew);
      }
    }
    xg0 = xn0; xg1 = xn1; xg2 = xn2; xg3 = xn3;
    // no trailing barrier: next iteration's pre-phase-A barrier orders preact/hist
  }
}

// ---------------- launcher ----------------
extern "C" void kernel_launch(void* const* d_in, const int* in_sizes, int n_in,
                              void* d_out, int out_size, void* d_ws, size_t ws_size,
                              hipStream_t stream){
  const float* x      = (const float*)d_in[0];
  const float* enc_w1 = (const float*)d_in[1];
  const float* enc_b1 = (const float*)d_in[2];
  const float* enc_w2 = (const float*)d_in[3];
  const float* enc_b2 = (const float*)d_in[4];
  const float* d_u_w  = (const float*)d_in[5];  const float* d_u_b = (const float*)d_in[6];
  const float* d_w_w  = (const float*)d_in[7];  const float* d_w_b = (const float*)d_in[8];
  const float* i_u_w  = (const float*)d_in[9];  const float* i_u_b = (const float*)d_in[10];
  const float* i_w_w  = (const float*)d_in[11]; const float* i_w_b = (const float*)d_in[12];
  const float* o_u_w  = (const float*)d_in[13]; const float* o_u_b = (const float*)d_in[14];
  const float* o_w_w  = (const float*)d_in[15]; const float* o_w_b = (const float*)d_in[16];
  const float* c_u_w  = (const float*)d_in[17]; const float* c_u_b = (const float*)d_in[18];
  const float* c_w_w  = (const float*)d_in[19]; const float* c_w_b = (const float*)d_in[20];
  const float* dec_w1 = (const float*)d_in[21]; const float* dec_b1 = (const float*)d_in[22];
  const float* dec_w2 = (const float*)d_in[23]; const float* dec_b2 = (const float*)d_in[24];

  char* ws = (char*)d_ws;
  u16*   xb     = (u16*)(ws + 0L);                 // 1024*50176*2
  u16*   w1b    = (u16*)(ws + 102760448L);         // 512*50176*2
  u16*   w2db   = (u16*)(ws + 154140672L);         // 50048*512*2
  u16*   h1b    = (u16*)(ws + 205389824L);         // 1024*512*2
  u16*   e_b    = (u16*)(ws + 206438400L);         // 1024*256*2
  u16*   wgb    = (u16*)(ws + 206962688L);         // 1024*256*2
  u16*   w2eb   = (u16*)(ws + 207486976L);         // 256*512*2
  u16*   wd1b   = (u16*)(ws + 207749120L);         // 512*256*2
  u16*   d1b    = (u16*)(ws + 208011264L);         // 1024*512*2
  u16*   hsb    = (u16*)(ws + 209059840L);         // 1024*256*2
  float* xw     = (float*)(ws + 209584128L);       // 1024*1024*4
  float* bws    = (float*)(ws + 213778432L);       // 1024*4
  u32*   upak   = (u32*)(ws + 213782528L);         // NSC*512*32 u32 = 524288 B
  float* out    = (float*)d_out;
  float* P      = (float*)d_out;                   // split-K partials (67 MB) reuse d_out
  // self-validating mailbox in the tail of d_out (overwritten only by the
  // decoder GEMM, which runs after the scan): 2 parities x 256 u32
  u32*   hmail  = (u32*)((char*)d_out + 200000000L); // 2048 B

  hipMemsetAsync(hmail, 0, 2048, stream);          // tag 0 never matches st >= 1

  conv_x   <<<dim3(49,1024), 256, 0, stream>>>(x, xb);
  conv_w1  <<<dim3(49,512),  256, 0, stream>>>(enc_w1, w1b);
  conv_misc<<<2048, 256, 0, stream>>>(enc_w2, dec_w1, d_w_w, i_w_w, o_w_w, c_w_w, w2eb, wd1b, wgb);
  pack_bias<<<4, 256, 0, stream>>>(d_u_b, d_w_b, i_u_b, i_w_b, o_u_b, o_w_b, c_u_b, c_w_b, bws);
  pack_u   <<<NSC, 512, 0, stream>>>(d_u_w, i_u_w, o_u_w, c_u_w, upak);

  gemm_bt<0><<<dim3(8,4,32), 256, 0, stream>>>(xb, w1b, nullptr, P, nullptr, 50176, 50176, 512, 49, 0);
  reduce1<<<2048, 256, 0, stream>>>(P, enc_b1, h1b);
  gemm_bt<1><<<dim3(8,2,1), 256, 0, stream>>>(h1b, w2eb, enc_b2, nullptr, e_b, 512, 512, 256, 16, 0);
  gemm_bt<2><<<dim3(8,8,1), 256, 0, stream>>>(e_b, wgb, bws, xw, nullptr, 256, 256, 1024, 8, 0);
  // cooperative scan (blocks 0..7) + dec_w2 bf16 convert (blocks 8..196)
  scan_kernel<<<197, 512, 0, stream>>>(upak, xw, hsb, dec_w2, w2db, hmail);
  gemm_bt<1><<<dim3(8,4,1), 256, 0, stream>>>(hsb, wd1b, dec_b1, nullptr, d1b, 256, 256, 512, 8, 0);
  gemm_bt<3><<<dim3(8,391,1), 256, 0, stream>>>(d1b, w2db, dec_b2, out, nullptr, 512, 512, 50000, 16, 50000);
}

// Round 17
// 2800.605 us; speedup vs baseline: 2.4680x; 2.4680x over previous
//
#include <hip/hip_runtime.h>

typedef unsigned int u32;
typedef unsigned short u16;
typedef __attribute__((ext_vector_type(4))) u32 u32x4;
typedef __attribute__((ext_vector_type(4))) u16 u16x4;
typedef __attribute__((ext_vector_type(8))) short bf16x8;
typedef __attribute__((ext_vector_type(4))) float f32x4;
typedef __attribute__((ext_vector_type(2))) _Float16 h2f;

#define NSC 8          // scan blocks
#define SLICE 32       // e per scan block
#define ROWS 128       // 4 gates * SLICE preact rows per block

__device__ __forceinline__ u16 f2bf(float x){
  u32 u = __builtin_bit_cast(u32, x);
  u = (u + 0x7fffu + ((u >> 16) & 1u)) >> 16;
  return (u16)u;
}
__device__ __forceinline__ u16 f2h(float x){
  _Float16 h = (_Float16)x;
  return __builtin_bit_cast(u16, h);
}
__device__ __forceinline__ float h2fl(u16 v){ return (float)__builtin_bit_cast(_Float16, v); }
__device__ __forceinline__ h2f as_h2(u32 v){ return __builtin_bit_cast(h2f, v); }
__device__ __forceinline__ float sigf(float x){ return 1.0f/(1.0f + __expf(-x)); }
__device__ __forceinline__ float tanh_f(float x){ float e = __expf(2.0f*x); return 1.0f - 2.0f/(e + 1.0f); }

__device__ __forceinline__ float dot2acc(u32 a, u32 b, float acc){
#if __has_builtin(__builtin_amdgcn_fdot2)
  return __builtin_amdgcn_fdot2(as_h2(a), as_h2(b), acc, false);
#else
  h2f ha = as_h2(a), hb = as_h2(b);
  return acc + (float)ha[0]*(float)hb[0] + (float)ha[1]*(float)hb[1];
#endif
}
__device__ __forceinline__ float dot4(u32x4 u, u32x4 h, float acc){
  acc = dot2acc(u[0], h[0], acc); acc = dot2acc(u[1], h[1], acc);
  acc = dot2acc(u[2], h[2], acc); acc = dot2acc(u[3], h[3], acc);
  return acc;
}

// ---------------- conversion kernels ----------------

// x (1024 x 50001) f32 -> xb (1024 x 50176) bf16, zero-pad cols [50000,50176)
__global__ void conv_x(const float* __restrict__ x, u16* __restrict__ xb){
  int col4 = (blockIdx.x*256 + threadIdx.x)*4;   // grid (49, 1024)
  int row  = blockIdx.y;
  const float* src = x + (long)row*50001 + col4;
  u16x4 v;
  if (col4 < 50000) { v[0]=f2bf(src[0]); v[1]=f2bf(src[1]); v[2]=f2bf(src[2]); v[3]=f2bf(src[3]); }
  else { v[0]=0; v[1]=0; v[2]=0; v[3]=0; }
  *(u16x4*)(xb + (long)row*50176 + col4) = v;
}

// enc_w1 (512 x 50000) f32 -> w1b (512 x 50176) bf16 padded
__global__ void conv_w1(const float* __restrict__ w, u16* __restrict__ wb){
  int col4 = (blockIdx.x*256 + threadIdx.x)*4;   // grid (49, 512)
  int row  = blockIdx.y;
  const float* src = w + (long)row*50000 + col4;
  u16x4 v;
  if (col4 < 50000) { v[0]=f2bf(src[0]); v[1]=f2bf(src[1]); v[2]=f2bf(src[2]); v[3]=f2bf(src[3]); }
  else { v[0]=0; v[1]=0; v[2]=0; v[3]=0; }
  *(u16x4*)(wb + (long)row*50176 + col4) = v;
}

// enc_w2 (256x512), dec_w1 (512x256), gate W_w stacked -> bf16
__global__ void conv_misc(const float* __restrict__ enc_w2, const float* __restrict__ dec_w1,
                          const float* __restrict__ dw, const float* __restrict__ iw,
                          const float* __restrict__ ow, const float* __restrict__ cw,
                          u16* __restrict__ w2eb, u16* __restrict__ wd1b, u16* __restrict__ wgb){
  int idx = blockIdx.x*256 + threadIdx.x;        // grid 2048
  if (idx < 131072) {
    w2eb[idx] = f2bf(enc_w2[idx]);
  } else if (idx < 262144) {
    int i = idx - 131072;
    wd1b[i] = f2bf(dec_w1[i]);
  } else {
    int i = idx - 262144;                        // 262144 elems: wgb[o][k], o = g*256+e
    int o = i >> 8, k = i & 255;
    int g = o >> 8, e = o & 255;
    const float* W = (g==0) ? dw : (g==1) ? iw : (g==2) ? ow : cw;
    wgb[i] = f2bf(W[e*256 + k]);
  }
}

// combined gate biases: bws[o] = u_b[e] + w_b[e]
__global__ void pack_bias(const float* dub, const float* dwb, const float* iub, const float* iwb,
                          const float* oub, const float* owb, const float* cub, const float* cwb,
                          float* __restrict__ bws){
  int o = blockIdx.x*256 + threadIdx.x;          // grid 4
  int g = o >> 8, e = o & 255;
  float v;
  if      (g==0) v = dub[e] + dwb[e];
  else if (g==1) v = iub[e] + iwb[e];
  else if (g==2) v = oub[e] + owb[e];
  else           v = cub[e] + cwb[e];
  bws[o] = v;
}

// Pack U for register residency in the scan.
// Block b, thread t: rq=t>>3 -> rows lr0=2rq, lr1=2rq+1 (lr in [0,128): gate
// g=lr>>5, e=b*32+(lr&31)); kc=t&7 -> k in [kc*32,(kc+1)*32).
// Quad q: row lr0 (q<4) / lr1 (q>=4), k-sub (q&3)*8 + [0,8) as 4 f16x2 words.
// upak layout: per-thread contiguous 32 u32 -> 8 coalesced dwordx4 loads.
__global__ void pack_u(const float* du, const float* iu, const float* ou, const float* cu,
                       u32* __restrict__ upak){
  int b = blockIdx.x;                            // grid NSC x 512
  int t = threadIdx.x;
  int rq = t >> 3, kc = t & 7;
  for (int q = 0; q < 8; ++q) {
    int lr = 2*rq + (q >> 2);
    int g = lr >> 5, e = b*SLICE + (lr & 31);
    const float* U = (g==0) ? du : (g==1) ? iu : (g==2) ? ou : cu;
    const float* row = U + e*256 + kc*32 + (q & 3)*8;
    for (int p = 0; p < 4; ++p) {
      u32 lo = f2h(row[p*2]);
      u32 hi = f2h(row[p*2+1]);
      upak[((long)(b*512 + t)*8 + q)*4 + p] = lo | (hi << 16);
    }
  }
}

// ---------------- MFMA GEMM: C = A @ B^T, A[M][K] bf16, B[N][K] bf16 ----------------
// EPI: 0 = store f32 partial at Cf + z*1024*ldc (split-K)
//      1 = bias + relu -> bf16 Cb
//      2 = bias -> f32 Cf
//      3 = bias + sigmoid -> f32 Cf with col < nGuard
template<int EPI>
__global__ __launch_bounds__(256)
void gemm_bt(const u16* __restrict__ A, const u16* __restrict__ B,
             const float* __restrict__ bias, float* __restrict__ Cf, u16* __restrict__ Cb,
             int lda, int ldb, int ldc, int kiters, int nGuard){
  __shared__ u16 As[128*32];
  __shared__ u16 Bs[128*32];
  const int tid = threadIdx.x;
  const int l = tid & 63;
  const int w = tid >> 6;
  const int wr = w >> 1, wc = w & 1;             // 2x2 wave grid, 64x64 per wave
  const long kchunk = (long)blockIdx.z * kiters * 32;
  const u16* Ab = A + (long)blockIdx.x*128*lda + kchunk;
  const u16* Bb = B + (long)blockIdx.y*128*ldb + kchunk;
  f32x4 acc[4][4];
#pragma unroll
  for (int m=0;m<4;m++)
#pragma unroll
    for (int n=0;n<4;n++) acc[m][n] = (f32x4){0.f,0.f,0.f,0.f};

  const int lr = l & 15, lk = l >> 4;
  for (int it = 0; it < kiters; ++it) {
    {
      int s = tid;
      int row = s >> 2, kg = s & 3;
      u32x4 va = *(const u32x4*)(Ab + (long)row*lda + (long)it*32 + kg*8);
      u32x4 vb = *(const u32x4*)(Bb + (long)row*ldb + (long)it*32 + kg*8);
      int sw = ((kg + row) & 3) * 8;
      *(u32x4*)&As[row*32 + sw] = va;
      *(u32x4*)&Bs[row*32 + sw] = vb;
      s = tid + 256;
      row = s >> 2; kg = s & 3;
      va = *(const u32x4*)(Ab + (long)row*lda + (long)it*32 + kg*8);
      vb = *(const u32x4*)(Bb + (long)row*ldb + (long)it*32 + kg*8);
      sw = ((kg + row) & 3) * 8;
      *(u32x4*)&As[row*32 + sw] = va;
      *(u32x4*)&Bs[row*32 + sw] = vb;
    }
    __syncthreads();
    bf16x8 af[4], bfr[4];
#pragma unroll
    for (int m=0;m<4;m++) {
      int row = wr*64 + m*16 + lr;
      af[m] = *(const bf16x8*)&As[row*32 + (((lk + row)&3)*8)];
    }
#pragma unroll
    for (int n=0;n<4;n++) {
      int row = wc*64 + n*16 + lr;
      bfr[n] = *(const bf16x8*)&Bs[row*32 + (((lk + row)&3)*8)];
    }
#pragma unroll
    for (int m=0;m<4;m++)
#pragma unroll
      for (int n=0;n<4;n++)
        acc[m][n] = __builtin_amdgcn_mfma_f32_16x16x32_bf16(af[m], bfr[n], acc[m][n], 0, 0, 0);
    __syncthreads();
  }
#pragma unroll
  for (int m=0;m<4;m++) {
#pragma unroll
    for (int n=0;n<4;n++) {
#pragma unroll
      for (int v=0;v<4;v++) {
        int r  = wr*64 + m*16 + lk*4 + v;
        int cn = wc*64 + n*16 + lr;
        long gr = (long)blockIdx.x*128 + r;
        long gc = (long)blockIdx.y*128 + cn;
        float val = acc[m][n][v];
        if (EPI == 0) {
          Cf[((long)blockIdx.z*1024 + gr)*ldc + gc] = val;
        } else if (EPI == 1) {
          float y = val + bias[gc];
          y = y > 0.f ? y : 0.f;
          Cb[gr*ldc + gc] = f2bf(y);
        } else if (EPI == 2) {
          Cf[gr*ldc + gc] = val + bias[gc];
        } else if (EPI == 3) {
          if (gc < nGuard) Cf[gr*ldc + gc] = sigf(val + bias[gc]);
        }
      }
    }
  }
}

// sum split-K partials + bias + relu -> bf16 h1b
__global__ void reduce1(const float* __restrict__ P, const float* __restrict__ b1,
                        u16* __restrict__ h1b){
  int idx = blockIdx.x*256 + threadIdx.x;        // grid 2048 -> 524288 = 1024*512
  float s = b1[idx & 511];
#pragma unroll
  for (int kc = 0; kc < 32; ++kc) s += P[(long)kc*524288 + idx];
  h1b[idx] = f2bf(s > 0.f ? s : 0.f);
}

// ---------------- 8-block cooperative scan (r11 protocol + U in registers) ----------------
// FINAL (r13 configuration, best measured: scan ~2520 us, total ~2819 us).
// Comm-protocol search summary: self-validating single-word poll + LDS
// broadcast is the floor (~5900 cy/step, cross-XCD coherence latency).
// Measured alternatives: contended counter 3370, tag-then-data 3137,
// same-XCD L2 9116 (non-coherent, fallback), 2-block 3113 (VGPR collapse),
// direct per-thread fetch 6610 (coherent-load traffic explosion).
// U lives in 8 named u32x4 register quads per thread (32 u32); h_lds padded
// to 80 B/chunk; xw prefetched one step ahead; phase B segmented product-scan.
__global__ __launch_bounds__(512) __attribute__((amdgpu_waves_per_eu(2,2)))
void scan_kernel(const u32* __restrict__ upak, const float* __restrict__ xw,
                 u16* __restrict__ hsb, const float* __restrict__ dec_w2,
                 u16* __restrict__ w2db, u32* __restrict__ hmail){
  __shared__ __align__(16) u16 h_lds[320];       // 8 chunks x 40 u16 (80 B stride)
  __shared__ float preact[ROWS];                 // 512 B
  __shared__ u16   hist[50*34];                  // 3400 B, stride 34, cols [0,32) used
  __shared__ float inv_lds[50];                  // 1/k table
  const int b = blockIdx.x;
  const int t = threadIdx.x;

  if (b >= NSC) {
    // dec_w2 (50000x512) f32 -> w2db (50048x512) bf16, rows >= 50000 zeroed.
    const long total = (50048L*512)/4;           // u16x4 groups
    const long stride = (long)(gridDim.x - NSC)*512;
    for (long g2 = (long)(b-NSC)*512 + t; g2 < total; g2 += stride) {
      long base = g2*4;
      long row = base >> 9;
      u16x4 v;
      if (row < 50000) {
        const float* s = dec_w2 + base;
        v[0]=f2bf(s[0]); v[1]=f2bf(s[1]); v[2]=f2bf(s[2]); v[3]=f2bf(s[3]);
      } else { v[0]=0; v[1]=0; v[2]=0; v[3]=0; }
      *(u16x4*)(w2db + base) = v;
    }
    return;
  }

  const int kc = t & 7;                          // phase A: k-chunk of 32
  const int rq = t >> 3;                         // phase A: rows 2rq, 2rq+1
  const int e_loc = t >> 3;                      // phase B (t<256): element (<32)
  const int tau = t & 7;                         // phase B lane-in-group
  const int e_glob = b*SLICE + (e_loc & (SLICE-1));

  // ---- U into registers: 8 named quads, 32 VGPRs, loaded once ----
  const long ubase = (long)(b*512 + t)*32;
  u32x4 Uq0 = *(const u32x4*)(upak + ubase + 0);
  u32x4 Uq1 = *(const u32x4*)(upak + ubase + 4);
  u32x4 Uq2 = *(const u32x4*)(upak + ubase + 8);
  u32x4 Uq3 = *(const u32x4*)(upak + ubase + 12);
  u32x4 Uq4 = *(const u32x4*)(upak + ubase + 16);
  u32x4 Uq5 = *(const u32x4*)(upak + ubase + 20);
  u32x4 Uq6 = *(const u32x4*)(upak + ubase + 24);
  u32x4 Uq7 = *(const u32x4*)(upak + ubase + 28);

  for (int i = t; i < 50*34; i += 512) hist[i] = 0;
  if (t < 320) h_lds[t] = 0;
  if (t < 50) inv_lds[t] = (t == 0) ? 1.0f : (1.0f/(float)t);
  __syncthreads();

  // xw for st=0 preloaded; in-loop we prefetch st+1 (consumed next iteration)
  float xg0=0.f, xg1=0.f, xg2=0.f, xg3=0.f;
  if (t < 256) {
    xg0 = xw[e_glob]; xg1 = xw[256 + e_glob]; xg2 = xw[512 + e_glob]; xg3 = xw[768 + e_glob];
  }

  for (int st = 0; st < 1024; ++st) {
    // ---- wait for h(st): each of 256 threads polls ITS self-validating word ----
    if (st > 0) {
      if (t < 256) {
        const u32* wp = hmail + ((st&1)<<8) + t;
        u32 v;
        do {
          v = __hip_atomic_load(wp, __ATOMIC_RELAXED, __HIP_MEMORY_SCOPE_AGENT);
        } while ((v >> 16) != (u32)st);
        h_lds[(t>>5)*40 + (t&31)] = (u16)v;      // padded: chunk stride 80 B
      }
      __syncthreads();
    }
    // prefetch xw(st+1): full step of latency cover; keeps poll vmcnt clean
    float xn0=0.f, xn1=0.f, xn2=0.f, xn3=0.f;
    if (st < 1023 && t < 256) {
      const float* xp = xw + (st+1)*1024;
      xn0 = xp[e_glob]; xn1 = xp[256 + e_glob]; xn2 = xp[512 + e_glob]; xn3 = xp[768 + e_glob];
    }
    // ---- phase A: preact[lr] = sum_k U[lr][k] * h[k] (register U, padded h) ----
    {
      u32x4 hb0 = *(const u32x4*)((const char*)h_lds + kc*80 +  0);
      u32x4 hb1 = *(const u32x4*)((const char*)h_lds + kc*80 + 16);
      u32x4 hb2 = *(const u32x4*)((const char*)h_lds + kc*80 + 32);
      u32x4 hb3 = *(const u32x4*)((const char*)h_lds + kc*80 + 48);
      float a0 = 0.f, a1 = 0.f;
      a0 = dot4(Uq0, hb0, a0); a0 = dot4(Uq1, hb1, a0);
      a0 = dot4(Uq2, hb2, a0); a0 = dot4(Uq3, hb3, a0);
      a1 = dot4(Uq4, hb0, a1); a1 = dot4(Uq5, hb1, a1);
      a1 = dot4(Uq6, hb2, a1); a1 = dot4(Uq7, hb3, a1);
      a0 += __shfl_xor(a0,1); a0 += __shfl_xor(a0,2); a0 += __shfl_xor(a0,4);
      a1 += __shfl_xor(a1,1); a1 += __shfl_xor(a1,2); a1 += __shfl_xor(a1,4);
      if (kc == 0) { preact[2*rq] = a0; preact[2*rq+1] = a1; }
    }
    __syncthreads();

    // ---- phase B (t<256): 8 lanes per element ----
    if (t < 256) {
      float pd = preact[0*SLICE + e_loc] + xg0;
      float pi = preact[1*SLICE + e_loc] + xg1;
      float po = preact[2*SLICE + e_loc] + xg2;
      float pc = preact[3*SLICE + e_loc] + xg3;
      float d  = 0.5f * sigf(pd);
      float gi = sigf(pi);
      float go = sigf(po);
      float ct = tanh_f(pc);
      float cur = gi * ct;
      // w_k = prod_{j<k} (d+j)/(j+1)  (== exp(gammaln(d+k)-gammaln(d)-gammaln(k+1)))
      // segmented product-scan: lane tau covers k in [7tau+1, 7tau+7]; tau=7 idle.
      float c = 1.f;
      if (tau < 7) {
#pragma unroll
        for (int m = 0; m < 7; ++m) {
          int j = 7*tau + m;                     // j <= 48
          c *= (d + (float)j) * inv_lds[j+1];
        }
      }
      float v = c;
      float s1 = __shfl_up(v,1,8); if (tau >= 1) v *= s1;
      float s2 = __shfl_up(v,2,8); if (tau >= 2) v *= s2;
      float s4 = __shfl_up(v,4,8); if (tau >= 4) v *= s4;
      float S = __shfl_up(v,1,8); if (tau == 0) S = 1.f;   // S = w_{7tau}
      int base = st % 50;
      float r = S, memp = 0.f;
      if (tau < 7) {
#pragma unroll
        for (int m = 0; m < 7; ++m) {
          int k = 7*tau + 1 + m;                 // 1..49
          r *= (d + (float)(k-1)) * inv_lds[k];  // r = w_k
          int sl = base - k; if (sl < 0) sl += 50;
          memp += r * h2fl(hist[sl*34 + e_loc]);
        }
      }
      memp += __shfl_xor(memp,1,8); memp += __shfl_xor(memp,2,8); memp += __shfl_xor(memp,4,8);
      float mem = memp + cur;                    // + k=0 term (w_0 = 1)
      float hnew = go * tanh_f(mem);
      if (tau == 0) {
        // publish FIRST (critical path), then local stores
        __hip_atomic_store(hmail + ((((st+1)&1))<<8) + e_glob,
                           (((u32)(st+1)) << 16) | (u32)f2h(hnew),
                           __ATOMIC_RELAXED, __HIP_MEMORY_SCOPE_AGENT);
        hist[base*34 + e_loc] = f2h(cur);
        hsb[st*256 + e_glob] = f2bf(hnew);
      }
    }
    xg0 = xn0; xg1 = xn1; xg2 = xn2; xg3 = xn3;
    // no trailing barrier: the next iteration's poll-barrier orders hist/h_lds
  }
}

// ---------------- launcher ----------------
extern "C" void kernel_launch(void* const* d_in, const int* in_sizes, int n_in,
                              void* d_out, int out_size, void* d_ws, size_t ws_size,
                              hipStream_t stream){
  const float* x      = (const float*)d_in[0];
  const float* enc_w1 = (const float*)d_in[1];
  const float* enc_b1 = (const float*)d_in[2];
  const float* enc_w2 = (const float*)d_in[3];
  const float* enc_b2 = (const float*)d_in[4];
  const float* d_u_w  = (const float*)d_in[5];  const float* d_u_b = (const float*)d_in[6];
  const float* d_w_w  = (const float*)d_in[7];  const float* d_w_b = (const float*)d_in[8];
  const float* i_u_w  = (const float*)d_in[9];  const float* i_u_b = (const float*)d_in[10];
  const float* i_w_w  = (const float*)d_in[11]; const float* i_w_b = (const float*)d_in[12];
  const float* o_u_w  = (const float*)d_in[13]; const float* o_u_b = (const float*)d_in[14];
  const float* o_w_w  = (const float*)d_in[15]; const float* o_w_b = (const float*)d_in[16];
  const float* c_u_w  = (const float*)d_in[17]; const float* c_u_b = (const float*)d_in[18];
  const float* c_w_w  = (const float*)d_in[19]; const float* c_w_b = (const float*)d_in[20];
  const float* dec_w1 = (const float*)d_in[21]; const float* dec_b1 = (const float*)d_in[22];
  const float* dec_w2 = (const float*)d_in[23]; const float* dec_b2 = (const float*)d_in[24];

  char* ws = (char*)d_ws;
  u16*   xb     = (u16*)(ws + 0L);                 // 1024*50176*2
  u16*   w1b    = (u16*)(ws + 102760448L);         // 512*50176*2
  u16*   w2db   = (u16*)(ws + 154140672L);         // 50048*512*2
  u16*   h1b    = (u16*)(ws + 205389824L);         // 1024*512*2
  u16*   e_b    = (u16*)(ws + 206438400L);         // 1024*256*2
  u16*   wgb    = (u16*)(ws + 206962688L);         // 1024*256*2
  u16*   w2eb   = (u16*)(ws + 207486976L);         // 256*512*2
  u16*   wd1b   = (u16*)(ws + 207749120L);         // 512*256*2
  u16*   d1b    = (u16*)(ws + 208011264L);         // 1024*512*2
  u16*   hsb    = (u16*)(ws + 209059840L);         // 1024*256*2
  float* xw     = (float*)(ws + 209584128L);       // 1024*1024*4
  float* bws    = (float*)(ws + 213778432L);       // 1024*4
  u32*   upak   = (u32*)(ws + 213782528L);         // NSC*512*32 u32 = 524288 B
  float* out    = (float*)d_out;
  float* P      = (float*)d_out;                   // split-K partials (67 MB) reuse d_out
  // self-validating mailbox in the tail of d_out (overwritten only by the
  // decoder GEMM, which runs after the scan): 2 parities x 256 u32
  u32*   hmail  = (u32*)((char*)d_out + 200000000L); // 2048 B

  hipMemsetAsync(hmail, 0, 2048, stream);          // tag 0 never matches st >= 1

  conv_x   <<<dim3(49,1024), 256, 0, stream>>>(x, xb);
  conv_w1  <<<dim3(49,512),  256, 0, stream>>>(enc_w1, w1b);
  conv_misc<<<2048, 256, 0, stream>>>(enc_w2, dec_w1, d_w_w, i_w_w, o_w_w, c_w_w, w2eb, wd1b, wgb);
  pack_bias<<<4, 256, 0, stream>>>(d_u_b, d_w_b, i_u_b, i_w_b, o_u_b, o_w_b, c_u_b, c_w_b, bws);
  pack_u   <<<NSC, 512, 0, stream>>>(d_u_w, i_u_w, o_u_w, c_u_w, upak);

  gemm_bt<0><<<dim3(8,4,32), 256, 0, stream>>>(xb, w1b, nullptr, P, nullptr, 50176, 50176, 512, 49, 0);
  reduce1<<<2048, 256, 0, stream>>>(P, enc_b1, h1b);
  gemm_bt<1><<<dim3(8,2,1), 256, 0, stream>>>(h1b, w2eb, enc_b2, nullptr, e_b, 512, 512, 256, 16, 0);
  gemm_bt<2><<<dim3(8,8,1), 256, 0, stream>>>(e_b, wgb, bws, xw, nullptr, 256, 256, 1024, 8, 0);
  // cooperative scan (blocks 0..7) + dec_w2 bf16 convert (blocks 8..196)
  scan_kernel<<<197, 512, 0, stream>>>(upak, xw, hsb, dec_w2, w2db, hmail);
  gemm_bt<1><<<dim3(8,4,1), 256, 0, stream>>>(hsb, wd1b, dec_b1, nullptr, d1b, 256, 256, 512, 8, 0);
  gemm_bt<3><<<dim3(8,391,1), 256, 0, stream>>>(d1b, w2db, dec_b2, out, nullptr, 512, 512, 50000, 16, 50000);
}